// Round 9
// baseline (425.263 us; speedup 1.0000x reference)
//
#include <hip/hip_runtime.h>
#include <stdint.h>

#define B_ 2
#define T_ 2048
#define D_ 1024
#define DI_ 2048
#define DS_ 16
#define MROWS (B_*T_)
#define NC_ 32            // scan chunks
#define CL_ (T_/NC_)      // 64 t per chunk
#define TT_ 32            // LDS tile (t)

typedef unsigned short u16;
typedef __attribute__((ext_vector_type(4))) float f32x4;
typedef __attribute__((ext_vector_type(8))) short short8;
typedef __attribute__((ext_vector_type(4))) unsigned short u16x4;

__device__ __forceinline__ float bf2f(u16 u) {
    union { uint32_t i; float f; } v; v.i = ((uint32_t)u) << 16; return v.f;
}
__device__ __forceinline__ u16 f2bf(float f) {
    union { float f; uint32_t i; } v; v.f = f;
    uint32_t r = v.i + 0x7fff + ((v.i >> 16) & 1);
    return (u16)(r >> 16);
}

// ---------------- f32 -> bf16 convert (vectorized x4) ----------------
__global__ __launch_bounds__(256) void cvt_kernel(const float* __restrict__ in,
                                                  u16* __restrict__ out, int n4) {
    int i = blockIdx.x * 256 + threadIdx.x;
    if (i < n4) {
        float4 v = ((const float4*)in)[i];
        u16x4 o;
        o.x = f2bf(v.x); o.y = f2bf(v.y); o.z = f2bf(v.z); o.w = f2bf(v.w);
        ((u16x4*)out)[i] = o;
    }
}

// ============ fused input GEMM: [xi | z | dt] = x @ [Win; Wdt]^T ============
// 128x128 tile, BK=32, 3-buffer LDS pipeline with counted vmcnt (never 0 in
// main loop), seg-swizzled LDS (bank-conflict-free), no XCD swizzle (L3-fit).
__global__ __launch_bounds__(256) void gemm_in(
    const u16* __restrict__ A, const u16* __restrict__ Win,
    const u16* __restrict__ Wdt,
    u16* __restrict__ xi, u16* __restrict__ z, u16* __restrict__ dtout,
    const float* __restrict__ b1, const float* __restrict__ b2) {
    __shared__ u16 lA[3][128 * 32];
    __shared__ u16 lB[3][128 * 32];
    const int K = D_;
    const int NK = K / 32;                 // 32 K-steps
    const int tid  = threadIdx.x;
    const int lane = tid & 63;
    const int wave = tid >> 6;
    const int wr = wave >> 1, wc = wave & 1;
    const int m0 = blockIdx.y * 128, n0 = blockIdx.x * 128;
    const int region = n0 >> 11;   // 0:xi 1:z 2:dt
    const u16* W = (region < 2) ? (Win + (size_t)n0 * K)
                                : (Wdt + (size_t)(n0 - 4096) * K);

    f32x4 acc[4][4];
#pragma unroll
    for (int i = 0; i < 4; ++i)
#pragma unroll
        for (int j = 0; j < 4; ++j) acc[i][j] = (f32x4){0.f, 0.f, 0.f, 0.f};

    // staging: involution seg swizzle (both-sides rule #21)
    const int srow = tid >> 2;
    const int sseg = tid & 3;
    const int gseg = sseg ^ ((srow >> 1) & 3);
    // fragment read swizzle
    const int fr = lane & 15, ks = lane >> 4;
    const int rsw = ks ^ ((fr >> 1) & 3);

    auto STAGE = [&](int buf, int k0) {
#pragma unroll
        for (int it = 0; it < 2; ++it) {
            int row = it * 64 + srow;
            const u16* sa = A + (size_t)(m0 + row) * K + k0 + gseg * 8;
            const u16* sw = W + (size_t)row * K + k0 + gseg * 8;
            __builtin_amdgcn_global_load_lds(
                (const __attribute__((address_space(1))) void*)sa,
                (__attribute__((address_space(3))) void*)(&lA[buf][row * 32 + sseg * 8]),
                16, 0, 0);
            __builtin_amdgcn_global_load_lds(
                (const __attribute__((address_space(1))) void*)sw,
                (__attribute__((address_space(3))) void*)(&lB[buf][row * 32 + sseg * 8]),
                16, 0, 0);
        }
    };
    auto COMPUTE = [&](int buf) {
        short8 af[4], bfr[4];
#pragma unroll
        for (int i = 0; i < 4; ++i) {
            af[i]  = *(const short8*)(&lA[buf][(wr * 64 + i * 16 + fr) * 32 + rsw * 8]);
            bfr[i] = *(const short8*)(&lB[buf][(wc * 64 + i * 16 + fr) * 32 + rsw * 8]);
        }
#pragma unroll
        for (int i = 0; i < 4; ++i)
#pragma unroll
            for (int j = 0; j < 4; ++j)
                acc[i][j] = __builtin_amdgcn_mfma_f32_16x16x32_bf16(
                    af[i], bfr[j], acc[i][j], 0, 0, 0);
    };

    // prologue: 3 stages in flight, wait for stage 0 only
    STAGE(0, 0); STAGE(1, 32); STAGE(2, 64);
    asm volatile("s_waitcnt vmcnt(8)" ::: "memory");
    __builtin_amdgcn_s_barrier();
    __builtin_amdgcn_sched_barrier(0);

    int cur = 0;
    for (int k = 0; k < NK - 3; ++k) {
        COMPUTE(cur);
        __builtin_amdgcn_s_barrier();           // all waves done reading cur
        __builtin_amdgcn_sched_barrier(0);
        STAGE(cur, (k + 3) * 32);               // overwrite cur with k+3
        asm volatile("s_waitcnt vmcnt(8)" ::: "memory");  // stage k+1 landed
        __builtin_amdgcn_s_barrier();
        __builtin_amdgcn_sched_barrier(0);
        cur = (cur == 2) ? 0 : cur + 1;
    }
    // peel: k = NK-3 (wait stage NK-2), NK-2 (wait stage NK-1), NK-1
    COMPUTE(cur);
    asm volatile("s_waitcnt vmcnt(4)" ::: "memory");
    __builtin_amdgcn_s_barrier();
    __builtin_amdgcn_sched_barrier(0);
    cur = (cur == 2) ? 0 : cur + 1;
    COMPUTE(cur);
    asm volatile("s_waitcnt vmcnt(0)" ::: "memory");
    __builtin_amdgcn_s_barrier();
    __builtin_amdgcn_sched_barrier(0);
    cur = (cur == 2) ? 0 : cur + 1;
    COMPUTE(cur);

    const int fq = lane >> 4;
#pragma unroll
    for (int i = 0; i < 4; ++i)
#pragma unroll
        for (int j = 0; j < 4; ++j) {
            int gnl = n0 + wc * 64 + j * 16 + fr;
#pragma unroll
            for (int r = 0; r < 4; ++r) {
                int gm = m0 + wr * 64 + i * 16 + fq * 4 + r;
                float v = acc[i][j][r];
                if (region == 0) {
                    xi[(size_t)gm * DI_ + gnl] = f2bf(v);
                } else if (region == 1) {
                    v = v / (1.f + __expf(-v));
                    z[(size_t)gm * DI_ + (gnl - 2048)] = f2bf(v);
                } else {
                    int gn = gnl - 4096;
                    v += b1[gn] + b2[gn];
                    v = (v > 20.f) ? v : log1pf(__expf(v));
                    dtout[(size_t)gm * DI_ + gn] = f2bf(v);
                }
            }
        }
}

// ---------------- out GEMM: y = normed @ Wout^T (f32 out) ----------------
__global__ __launch_bounds__(256) void gemm_out(
    const u16* __restrict__ A, const u16* __restrict__ W,
    float* __restrict__ out, int M, int N, int K) {
    __shared__ u16 lA[3][128 * 32];
    __shared__ u16 lB[3][128 * 32];
    const int NK = K / 32;
    const int tid  = threadIdx.x;
    const int lane = tid & 63;
    const int wave = tid >> 6;
    const int wr = wave >> 1, wc = wave & 1;
    const int m0 = blockIdx.y * 128, n0 = blockIdx.x * 128;

    f32x4 acc[4][4];
#pragma unroll
    for (int i = 0; i < 4; ++i)
#pragma unroll
        for (int j = 0; j < 4; ++j) acc[i][j] = (f32x4){0.f, 0.f, 0.f, 0.f};

    const int srow = tid >> 2;
    const int sseg = tid & 3;
    const int gseg = sseg ^ ((srow >> 1) & 3);
    const int fr = lane & 15, ks = lane >> 4;
    const int rsw = ks ^ ((fr >> 1) & 3);

    auto STAGE = [&](int buf, int k0) {
#pragma unroll
        for (int it = 0; it < 2; ++it) {
            int row = it * 64 + srow;
            const u16* sa = A + (size_t)(m0 + row) * K + k0 + gseg * 8;
            const u16* sw = W + (size_t)(n0 + row) * K + k0 + gseg * 8;
            __builtin_amdgcn_global_load_lds(
                (const __attribute__((address_space(1))) void*)sa,
                (__attribute__((address_space(3))) void*)(&lA[buf][row * 32 + sseg * 8]),
                16, 0, 0);
            __builtin_amdgcn_global_load_lds(
                (const __attribute__((address_space(1))) void*)sw,
                (__attribute__((address_space(3))) void*)(&lB[buf][row * 32 + sseg * 8]),
                16, 0, 0);
        }
    };
    auto COMPUTE = [&](int buf) {
        short8 af[4], bfr[4];
#pragma unroll
        for (int i = 0; i < 4; ++i) {
            af[i]  = *(const short8*)(&lA[buf][(wr * 64 + i * 16 + fr) * 32 + rsw * 8]);
            bfr[i] = *(const short8*)(&lB[buf][(wc * 64 + i * 16 + fr) * 32 + rsw * 8]);
        }
#pragma unroll
        for (int i = 0; i < 4; ++i)
#pragma unroll
            for (int j = 0; j < 4; ++j)
                acc[i][j] = __builtin_amdgcn_mfma_f32_16x16x32_bf16(
                    af[i], bfr[j], acc[i][j], 0, 0, 0);
    };

    STAGE(0, 0); STAGE(1, 32); STAGE(2, 64);
    asm volatile("s_waitcnt vmcnt(8)" ::: "memory");
    __builtin_amdgcn_s_barrier();
    __builtin_amdgcn_sched_barrier(0);

    int cur = 0;
    for (int k = 0; k < NK - 3; ++k) {
        COMPUTE(cur);
        __builtin_amdgcn_s_barrier();
        __builtin_amdgcn_sched_barrier(0);
        STAGE(cur, (k + 3) * 32);
        asm volatile("s_waitcnt vmcnt(8)" ::: "memory");
        __builtin_amdgcn_s_barrier();
        __builtin_amdgcn_sched_barrier(0);
        cur = (cur == 2) ? 0 : cur + 1;
    }
    COMPUTE(cur);
    asm volatile("s_waitcnt vmcnt(4)" ::: "memory");
    __builtin_amdgcn_s_barrier();
    __builtin_amdgcn_sched_barrier(0);
    cur = (cur == 2) ? 0 : cur + 1;
    COMPUTE(cur);
    asm volatile("s_waitcnt vmcnt(0)" ::: "memory");
    __builtin_amdgcn_s_barrier();
    __builtin_amdgcn_sched_barrier(0);
    cur = (cur == 2) ? 0 : cur + 1;
    COMPUTE(cur);

    const int fq = lane >> 4;
#pragma unroll
    for (int i = 0; i < 4; ++i)
#pragma unroll
        for (int j = 0; j < 4; ++j) {
            int gn = n0 + wc * 64 + j * 16 + fr;
#pragma unroll
            for (int r = 0; r < 4; ++r) {
                int gm = m0 + wr * 64 + i * 16 + fq * 4 + r;
                out[(size_t)gm * N + gn] = acc[i][j][r];
            }
        }
}

// ---------------- Bm / C projections (N=16 each, fp32) ----------------
__global__ __launch_bounds__(256) void bc_kernel(
    const float* __restrict__ x, const float* __restrict__ WB,
    const float* __restrict__ WC, float* __restrict__ Bm, float* __restrict__ Cm) {
    __shared__ float xs[32][65];
    __shared__ float ws[32][65];
    int m0 = blockIdx.x * 32;
    int tid = threadIdx.x;
    int o = tid & 31, mg = tid >> 5;
    float acc[4] = {0.f, 0.f, 0.f, 0.f};
    for (int k0 = 0; k0 < D_; k0 += 64) {
        __syncthreads();
#pragma unroll
        for (int j = 0; j < 8; ++j) {
            int f = j * 256 + tid;
            int r = f >> 6, kk = f & 63;
            xs[r][kk] = x[(size_t)(m0 + r) * D_ + k0 + kk];
            ws[r][kk] = (r < 16) ? WB[(size_t)r * D_ + k0 + kk]
                                 : WC[(size_t)(r - 16) * D_ + k0 + kk];
        }
        __syncthreads();
#pragma unroll 8
        for (int kk = 0; kk < 64; ++kk) {
            float wv = ws[o][kk];
#pragma unroll
            for (int r = 0; r < 4; ++r)
                acc[r] = fmaf(xs[mg * 4 + r][kk], wv, acc[r]);
        }
    }
#pragma unroll
    for (int r = 0; r < 4; ++r) {
        int m = m0 + mg * 4 + r;
        if (o < 16) Bm[(size_t)m * DS_ + o] = acc[r];
        else        Cm[(size_t)m * DS_ + (o - 16)] = acc[r];
    }
}

// ============ chunked scan, thread-owns-d layout ============
// pass 1 — per-chunk decay products P[s] and zero-input responses Z[s]
__global__ __launch_bounds__(256) void scan1_kernel(
    const u16* __restrict__ dt, const u16* __restrict__ xi,
    const float* __restrict__ Bm, const float* __restrict__ A_log,
    float* __restrict__ P, float* __restrict__ Z) {
    const int c = blockIdx.x, dblk = blockIdx.y, b = blockIdx.z;
    const int tid = threadIdx.x;
    const int d = dblk * 256 + tid;
    __shared__ u16 sdt[TT_ * 256];
    __shared__ u16 sxi[TT_ * 256];
    __shared__ float sB[TT_ * 16];
    float A2[16], st[16], Pp[16];
#pragma unroll
    for (int s = 0; s < 16; ++s) {
        A2[s] = -0.5f * __expf(A_log[(size_t)d * DS_ + s]);
        st[s] = 0.f; Pp[s] = 1.f;
    }
    const size_t tb = (size_t)b * T_;
    for (int t0 = c * CL_; t0 < (c + 1) * CL_; t0 += TT_) {
        __syncthreads();
#pragma unroll
        for (int r = 0; r < 4; ++r) {
            int flat = r * 2048 + tid * 8;
            int row = flat >> 8, col = flat & 255;
            const u16* s1 = dt + (tb + t0 + row) * DI_ + dblk * 256 + col;
            const u16* s2 = xi + (tb + t0 + row) * DI_ + dblk * 256 + col;
            __builtin_amdgcn_global_load_lds(
                (const __attribute__((address_space(1))) void*)s1,
                (__attribute__((address_space(3))) void*)(sdt + flat), 16, 0, 0);
            __builtin_amdgcn_global_load_lds(
                (const __attribute__((address_space(1))) void*)s2,
                (__attribute__((address_space(3))) void*)(sxi + flat), 16, 0, 0);
        }
        *(float2*)(sB + tid * 2) = *(const float2*)(Bm + (tb + t0) * DS_ + tid * 2);
        __syncthreads();
#pragma unroll 2
        for (int tt = 0; tt < TT_; ++tt) {
            float dtv = bf2f(sdt[tt * 256 + tid]);
            float xiv = bf2f(sxi[tt * 256 + tid]);
            float dxv = dtv * xiv;
            float bv[16];
            *(float4*)&bv[0]  = *(const float4*)(sB + tt * 16);
            *(float4*)&bv[4]  = *(const float4*)(sB + tt * 16 + 4);
            *(float4*)&bv[8]  = *(const float4*)(sB + tt * 16 + 8);
            *(float4*)&bv[12] = *(const float4*)(sB + tt * 16 + 12);
#pragma unroll
            for (int s = 0; s < 16; ++s) {
                float a2   = fmaf(dtv, -A2[s], 1.f);
                float inv  = __builtin_amdgcn_rcpf(a2);
                float abar = fmaf(2.f, inv, -1.f);
                st[s] = fmaf(abar, st[s], (inv * bv[s]) * dxv);
                Pp[s] *= abar;
            }
        }
    }
    size_t base = (((size_t)b * DI_ + d) * NC_ + c) * 16;
#pragma unroll
    for (int q = 0; q < 4; ++q) {
        *(float4*)(P + base + q * 4) = (float4){Pp[q*4], Pp[q*4+1], Pp[q*4+2], Pp[q*4+3]};
        *(float4*)(Z + base + q * 4) = (float4){st[q*4], st[q*4+1], st[q*4+2], st[q*4+3]};
    }
}

// pass 2 — serial combine over chunks; writes chunk-init states I in-place into P
__global__ __launch_bounds__(256) void scan2_kernel(
    float* __restrict__ P, const float* __restrict__ Z,
    float* __restrict__ st_out) {
    size_t idx = (size_t)blockIdx.x * 256 + threadIdx.x;   // (b*DI+d)*16+s
    size_t bd = idx >> 4;
    int s = (int)(idx & 15);
    float cur = 0.f;
    for (int c = 0; c < NC_; ++c) {
        size_t a = (bd * NC_ + c) * 16 + s;
        float p = P[a], zv = Z[a];
        P[a] = cur;                       // I: state at chunk start
        cur = fmaf(p, cur, zv);
    }
    st_out[idx] = cur;
}

// pass 3 — recompute with init states, emit dot-product outputs
__global__ __launch_bounds__(256) void scan3_kernel(
    const u16* __restrict__ dt, const u16* __restrict__ xi,
    const float* __restrict__ Bm, const float* __restrict__ Cm,
    const float* __restrict__ A_log, const float* __restrict__ I,
    u16* __restrict__ so) {
    const int c = blockIdx.x, dblk = blockIdx.y, b = blockIdx.z;
    const int tid = threadIdx.x;
    const int d = dblk * 256 + tid;
    __shared__ u16 sdt[TT_ * 256];
    __shared__ u16 sxi[TT_ * 256];
    __shared__ float sB[TT_ * 16];
    __shared__ float sC[TT_ * 16];
    float A2[16], st[16];
#pragma unroll
    for (int s = 0; s < 16; ++s)
        A2[s] = -0.5f * __expf(A_log[(size_t)d * DS_ + s]);
    size_t base = (((size_t)b * DI_ + d) * NC_ + c) * 16;
#pragma unroll
    for (int q = 0; q < 4; ++q) {
        float4 v = *(const float4*)(I + base + q * 4);
        st[q*4] = v.x; st[q*4+1] = v.y; st[q*4+2] = v.z; st[q*4+3] = v.w;
    }
    const size_t tb = (size_t)b * T_;
    for (int t0 = c * CL_; t0 < (c + 1) * CL_; t0 += TT_) {
        __syncthreads();
#pragma unroll
        for (int r = 0; r < 4; ++r) {
            int flat = r * 2048 + tid * 8;
            int row = flat >> 8, col = flat & 255;
            const u16* s1 = dt + (tb + t0 + row) * DI_ + dblk * 256 + col;
            const u16* s2 = xi + (tb + t0 + row) * DI_ + dblk * 256 + col;
            __builtin_amdgcn_global_load_lds(
                (const __attribute__((address_space(1))) void*)s1,
                (__attribute__((address_space(3))) void*)(sdt + flat), 16, 0, 0);
            __builtin_amdgcn_global_load_lds(
                (const __attribute__((address_space(1))) void*)s2,
                (__attribute__((address_space(3))) void*)(sxi + flat), 16, 0, 0);
        }
        *(float2*)(sB + tid * 2) = *(const float2*)(Bm + (tb + t0) * DS_ + tid * 2);
        *(float2*)(sC + tid * 2) = *(const float2*)(Cm + (tb + t0) * DS_ + tid * 2);
        __syncthreads();
#pragma unroll 2
        for (int tt = 0; tt < TT_; ++tt) {
            float dtv = bf2f(sdt[tt * 256 + tid]);
            float xiv = bf2f(sxi[tt * 256 + tid]);
            float dxv = dtv * xiv;
            float bv[16], cv[16];
            *(float4*)&bv[0]  = *(const float4*)(sB + tt * 16);
            *(float4*)&bv[4]  = *(const float4*)(sB + tt * 16 + 4);
            *(float4*)&bv[8]  = *(const float4*)(sB + tt * 16 + 8);
            *(float4*)&bv[12] = *(const float4*)(sB + tt * 16 + 12);
            *(float4*)&cv[0]  = *(const float4*)(sC + tt * 16);
            *(float4*)&cv[4]  = *(const float4*)(sC + tt * 16 + 4);
            *(float4*)&cv[8]  = *(const float4*)(sC + tt * 16 + 8);
            *(float4*)&cv[12] = *(const float4*)(sC + tt * 16 + 12);
            float acc = 0.f;
#pragma unroll
            for (int s = 0; s < 16; ++s) {
                float a2   = fmaf(dtv, -A2[s], 1.f);
                float inv  = __builtin_amdgcn_rcpf(a2);
                float abar = fmaf(2.f, inv, -1.f);
                st[s] = fmaf(abar, st[s], (inv * bv[s]) * dxv);
                acc = fmaf(st[s], cv[s], acc);
            }
            so[(tb + t0 + tt) * DI_ + d] = f2bf(acc);
        }
    }
}

// ---------------- gated LayerNorm -> bf16 normed ----------------
__global__ __launch_bounds__(256) void ln_kernel(
    const u16* __restrict__ so, const u16* __restrict__ z,
    const float* __restrict__ gamma, const float* __restrict__ beta,
    u16* __restrict__ normed) {
    int m = blockIdx.x;
    int tid = threadIdx.x;
    size_t base = (size_t)m * DI_;
    float v[8];
    float s = 0.f, s2 = 0.f;
#pragma unroll
    for (int j = 0; j < 8; ++j) {
        int i = tid + j * 256;
        float val = bf2f(so[base + i]) * bf2f(z[base + i]);
        v[j] = val; s += val; s2 += val * val;
    }
#pragma unroll
    for (int off = 32; off; off >>= 1) {
        s  += __shfl_xor(s,  off);
        s2 += __shfl_xor(s2, off);
    }
    __shared__ float rs[4], rq[4];
    int wave = tid >> 6;
    if ((tid & 63) == 0) { rs[wave] = s; rq[wave] = s2; }
    __syncthreads();
    s  = rs[0] + rs[1] + rs[2] + rs[3];
    s2 = rq[0] + rq[1] + rq[2] + rq[3];
    float mu  = s * (1.f / DI_);
    float var = s2 * (1.f / DI_) - mu * mu;
    float rstd = rsqrtf(var + 1e-5f);
#pragma unroll
    for (int j = 0; j < 8; ++j) {
        int i = tid + j * 256;
        float nv = (v[j] - mu) * rstd * gamma[i] + beta[i];
        normed[base + i] = f2bf(nv);
    }
}

extern "C" void kernel_launch(void* const* d_in, const int* in_sizes, int n_in,
                              void* d_out, int out_size, void* d_ws, size_t ws_size,
                              hipStream_t stream) {
    const float* x       = (const float*)d_in[0];
    const float* Win     = (const float*)d_in[1];
    const float* A_log   = (const float*)d_in[2];
    const float* WB      = (const float*)d_in[3];
    const float* WC      = (const float*)d_in[4];
    const float* Wdt     = (const float*)d_in[5];
    const float* bdt     = (const float*)d_in[6];
    const float* dt_bias = (const float*)d_in[7];
    const float* gamma   = (const float*)d_in[8];
    const float* beta    = (const float*)d_in[9];
    const float* Wout    = (const float*)d_in[10];

    float* y_out     = (float*)d_out;
    float* state_out = y_out + (size_t)B_ * T_ * D_;

    char* ws = (char*)d_ws;
    u16* xi_bf   = (u16*)(ws + 0);            // 16 MB
    u16* z_bf    = (u16*)(ws + 16777216);     // 16 MB
    u16* dt_bf   = (u16*)(ws + 33554432);     // 16 MB
    u16* so_bf   = (u16*)(ws + 50331648);     // 16 MB
    u16* nm_bf   = (u16*)(ws + 67108864);     // 16 MB
    u16* x_bf    = (u16*)(ws + 83886080);     // 8 MB  (dead after GEMMs -> P/I)
    u16* win_bf  = (u16*)(ws + 92274688);     // 8 MB  (dead after GEMMs -> Z)
    u16* wdt_bf  = (u16*)(ws + 100663296);    // 4 MB
    u16* wout_bf = (u16*)(ws + 104857600);    // 4 MB
    float* BmB   = (float*)(ws + 109051904);  // 256 KB
    float* CmB   = (float*)(ws + 109314048);  // 256 KB

    // P (8 MB, becomes I in-place) and Z (8 MB) alias dead x_bf / win_bf
    float* Pc = (float*)(ws + 83886080);
    float* Zc = (float*)(ws + 92274688);

    {
        int n4;
        n4 = (B_ * T_ * D_) / 4;
        cvt_kernel<<<(n4 + 255) / 256, 256, 0, stream>>>(x, x_bf, n4);
        n4 = (2 * DI_ * D_) / 4;
        cvt_kernel<<<(n4 + 255) / 256, 256, 0, stream>>>(Win, win_bf, n4);
        n4 = (DI_ * D_) / 4;
        cvt_kernel<<<(n4 + 255) / 256, 256, 0, stream>>>(Wdt, wdt_bf, n4);
        n4 = (D_ * DI_) / 4;
        cvt_kernel<<<(n4 + 255) / 256, 256, 0, stream>>>(Wout, wout_bf, n4);
    }

    dim3 blk(256);
    // fused [xi | z | dt]
    gemm_in<<<dim3(6144 / 128, MROWS / 128), blk, 0, stream>>>(
        x_bf, win_bf, wdt_bf, xi_bf, z_bf, dt_bf, bdt, dt_bias);
    bc_kernel<<<MROWS / 32, 256, 0, stream>>>(x, WB, WC, BmB, CmB);

    // chunked scan (3 passes) — x_bf/win_bf dead from here
    scan1_kernel<<<dim3(NC_, DI_ / 256, B_), blk, 0, stream>>>(
        dt_bf, xi_bf, BmB, A_log, Pc, Zc);
    scan2_kernel<<<(B_ * DI_ * DS_) / 256, blk, 0, stream>>>(
        Pc, Zc, state_out);
    scan3_kernel<<<dim3(NC_, DI_ / 256, B_), blk, 0, stream>>>(
        dt_bf, xi_bf, BmB, CmB, A_log, Pc, so_bf);

    ln_kernel<<<MROWS, 256, 0, stream>>>(so_bf, z_bf, gamma, beta, nm_bf);
    gemm_out<<<dim3(D_ / 128, MROWS / 128), blk, 0, stream>>>(
        nm_bf, wout_bf, y_out, MROWS, D_, DI_);
}

// Round 11
// 409.116 us; speedup vs baseline: 1.0395x; 1.0395x over previous
//
#include <hip/hip_runtime.h>
#include <stdint.h>

#define B_ 2
#define T_ 2048
#define D_ 1024
#define DI_ 2048
#define DS_ 16
#define MROWS (B_*T_)
#define NC_ 32            // scan chunks
#define CL_ (T_/NC_)      // 64 t per chunk
#define TT_ 32            // LDS tile (t)

typedef unsigned short u16;
typedef __attribute__((ext_vector_type(4))) float f32x4;
typedef __attribute__((ext_vector_type(8))) short short8;
typedef __attribute__((ext_vector_type(4))) unsigned short u16x4;

__device__ __forceinline__ float bf2f(u16 u) {
    union { uint32_t i; float f; } v; v.i = ((uint32_t)u) << 16; return v.f;
}
__device__ __forceinline__ u16 f2bf(float f) {
    union { float f; uint32_t i; } v; v.f = f;
    uint32_t r = v.i + 0x7fff + ((v.i >> 16) & 1);
    return (u16)(r >> 16);
}

// ---------------- f32 -> bf16 convert (vectorized x4) ----------------
__global__ __launch_bounds__(256) void cvt_kernel(const float* __restrict__ in,
                                                  u16* __restrict__ out, int n4) {
    int i = blockIdx.x * 256 + threadIdx.x;
    if (i < n4) {
        float4 v = ((const float4*)in)[i];
        u16x4 o;
        o.x = f2bf(v.x); o.y = f2bf(v.y); o.z = f2bf(v.z); o.w = f2bf(v.w);
        ((u16x4*)out)[i] = o;
    }
}

// ============ fused input GEMM: [xi | z | dt] = x @ [Win; Wdt]^T ============
// BM=256 x BN=128 tile, BK=32, 8 waves (512 thr), double-buffered LDS,
// prefetch-before-compute, ONE __syncthreads per K-step (R7 schedule, best
// measured), seg-swizzled LDS (conflict-free), no XCD swizzle (L2-resident).
// A/B test vs R9: per-wave work identical; block-K-step count halved.
__global__ __launch_bounds__(512) void gemm_in(
    const u16* __restrict__ A, const u16* __restrict__ Win,
    const u16* __restrict__ Wdt,
    u16* __restrict__ xi, u16* __restrict__ z, u16* __restrict__ dtout,
    const float* __restrict__ b1, const float* __restrict__ b2) {
    __shared__ u16 lA[2][256 * 32];
    __shared__ u16 lB[2][128 * 32];
    const int K = D_;
    const int tid  = threadIdx.x;
    const int lane = tid & 63;
    const int wave = tid >> 6;          // 0..7
    const int wr = wave >> 1;           // 0..3 : 64-row band of 256
    const int wc = wave & 1;            // 0..1 : 64-col band of 128
    const int m0 = blockIdx.y * 256, n0 = blockIdx.x * 128;
    const int region = n0 >> 11;        // 0:xi 1:z 2:dt
    const u16* W = (region < 2) ? (Win + (size_t)n0 * K)
                                : (Wdt + (size_t)(n0 - 4096) * K);

    f32x4 acc[4][4];
#pragma unroll
    for (int i = 0; i < 4; ++i)
#pragma unroll
        for (int j = 0; j < 4; ++j) acc[i][j] = (f32x4){0.f, 0.f, 0.f, 0.f};

    // staging: 512 thr -> row = tid>>2 (0..127), seg = tid&3; involution swizzle
    const int srow = tid >> 2;
    const int sseg = tid & 3;
    const int gseg = sseg ^ ((srow >> 1) & 3);
    // fragment read swizzle (row base multiples of 16 -> depends on fr only)
    const int fr = lane & 15, ks = lane >> 4;
    const int rsw = ks ^ ((fr >> 1) & 3);

    auto STAGE = [&](int buf, int k0) {
#pragma unroll
        for (int it = 0; it < 2; ++it) {           // A: 256 rows, 2 issues
            int row = it * 128 + srow;
            const u16* sa = A + (size_t)(m0 + row) * K + k0 + gseg * 8;
            __builtin_amdgcn_global_load_lds(
                (const __attribute__((address_space(1))) void*)sa,
                (__attribute__((address_space(3))) void*)(&lA[buf][row * 32 + sseg * 8]),
                16, 0, 0);
        }
        const u16* sw = W + (size_t)srow * K + k0 + gseg * 8;   // B: 128 rows
        __builtin_amdgcn_global_load_lds(
            (const __attribute__((address_space(1))) void*)sw,
            (__attribute__((address_space(3))) void*)(&lB[buf][srow * 32 + sseg * 8]),
            16, 0, 0);
    };

    STAGE(0, 0);
    __syncthreads();
    int cur = 0;
    for (int k0 = 0; k0 < K; k0 += 32) {
        if (k0 + 32 < K) STAGE(cur ^ 1, k0 + 32);   // prefetch overlaps compute
        short8 af[4], bfr[4];
#pragma unroll
        for (int i = 0; i < 4; ++i) {
            af[i]  = *(const short8*)(&lA[cur][(wr * 64 + i * 16 + fr) * 32 + rsw * 8]);
            bfr[i] = *(const short8*)(&lB[cur][(wc * 64 + i * 16 + fr) * 32 + rsw * 8]);
        }
#pragma unroll
        for (int i = 0; i < 4; ++i)
#pragma unroll
            for (int j = 0; j < 4; ++j)
                acc[i][j] = __builtin_amdgcn_mfma_f32_16x16x32_bf16(
                    af[i], bfr[j], acc[i][j], 0, 0, 0);
        __syncthreads();   // drains prefetch + ends reads of cur; 1 barrier/step
        cur ^= 1;
    }

    const int fq = lane >> 4;
#pragma unroll
    for (int i = 0; i < 4; ++i)
#pragma unroll
        for (int j = 0; j < 4; ++j) {
            int gnl = n0 + wc * 64 + j * 16 + fr;
#pragma unroll
            for (int r = 0; r < 4; ++r) {
                int gm = m0 + wr * 64 + i * 16 + fq * 4 + r;
                float v = acc[i][j][r];
                if (region == 0) {
                    xi[(size_t)gm * DI_ + gnl] = f2bf(v);
                } else if (region == 1) {
                    v = v / (1.f + __expf(-v));
                    z[(size_t)gm * DI_ + (gnl - 2048)] = f2bf(v);
                } else {
                    int gn = gnl - 4096;
                    v += b1[gn] + b2[gn];
                    v = (v > 20.f) ? v : log1pf(__expf(v));
                    dtout[(size_t)gm * DI_ + gn] = f2bf(v);
                }
            }
        }
}

// ---------------- out GEMM: y = normed @ Wout^T (f32 out) ----------------
// 128x128, dbuf-2, 1 barrier/K-step, seg-swizzle, no XCD swizzle.
__global__ __launch_bounds__(256) void gemm_out(
    const u16* __restrict__ A, const u16* __restrict__ W,
    float* __restrict__ out, int M, int N, int K) {
    __shared__ u16 lA[2][128 * 32];
    __shared__ u16 lB[2][128 * 32];
    const int tid  = threadIdx.x;
    const int lane = tid & 63;
    const int wave = tid >> 6;
    const int wr = wave >> 1, wc = wave & 1;
    const int m0 = blockIdx.y * 128, n0 = blockIdx.x * 128;

    f32x4 acc[4][4];
#pragma unroll
    for (int i = 0; i < 4; ++i)
#pragma unroll
        for (int j = 0; j < 4; ++j) acc[i][j] = (f32x4){0.f, 0.f, 0.f, 0.f};

    const int srow = tid >> 2;
    const int sseg = tid & 3;
    const int gseg = sseg ^ ((srow >> 1) & 3);
    const int fr = lane & 15, ks = lane >> 4;
    const int rsw = ks ^ ((fr >> 1) & 3);

    auto STAGE = [&](int buf, int k0) {
#pragma unroll
        for (int it = 0; it < 2; ++it) {
            int row = it * 64 + srow;
            const u16* sa = A + (size_t)(m0 + row) * K + k0 + gseg * 8;
            const u16* sw = W + (size_t)(n0 + row) * K + k0 + gseg * 8;
            __builtin_amdgcn_global_load_lds(
                (const __attribute__((address_space(1))) void*)sa,
                (__attribute__((address_space(3))) void*)(&lA[buf][row * 32 + sseg * 8]),
                16, 0, 0);
            __builtin_amdgcn_global_load_lds(
                (const __attribute__((address_space(1))) void*)sw,
                (__attribute__((address_space(3))) void*)(&lB[buf][row * 32 + sseg * 8]),
                16, 0, 0);
        }
    };

    STAGE(0, 0);
    __syncthreads();
    int cur = 0;
    for (int k0 = 0; k0 < K; k0 += 32) {
        if (k0 + 32 < K) STAGE(cur ^ 1, k0 + 32);
        short8 af[4], bfr[4];
#pragma unroll
        for (int i = 0; i < 4; ++i) {
            af[i]  = *(const short8*)(&lA[cur][(wr * 64 + i * 16 + fr) * 32 + rsw * 8]);
            bfr[i] = *(const short8*)(&lB[cur][(wc * 64 + i * 16 + fr) * 32 + rsw * 8]);
        }
#pragma unroll
        for (int i = 0; i < 4; ++i)
#pragma unroll
            for (int j = 0; j < 4; ++j)
                acc[i][j] = __builtin_amdgcn_mfma_f32_16x16x32_bf16(
                    af[i], bfr[j], acc[i][j], 0, 0, 0);
        __syncthreads();
        cur ^= 1;
    }

    const int fq = lane >> 4;
#pragma unroll
    for (int i = 0; i < 4; ++i)
#pragma unroll
        for (int j = 0; j < 4; ++j) {
            int gn = n0 + wc * 64 + j * 16 + fr;
#pragma unroll
            for (int r = 0; r < 4; ++r) {
                int gm = m0 + wr * 64 + i * 16 + fq * 4 + r;
                out[(size_t)gm * N + gn] = acc[i][j][r];
            }
        }
}

// ---------------- Bm / C projections (N=16 each, fp32) ----------------
__global__ __launch_bounds__(256) void bc_kernel(
    const float* __restrict__ x, const float* __restrict__ WB,
    const float* __restrict__ WC, float* __restrict__ Bm, float* __restrict__ Cm) {
    __shared__ float xs[32][65];
    __shared__ float ws[32][65];
    int m0 = blockIdx.x * 32;
    int tid = threadIdx.x;
    int o = tid & 31, mg = tid >> 5;
    float acc[4] = {0.f, 0.f, 0.f, 0.f};
    for (int k0 = 0; k0 < D_; k0 += 64) {
        __syncthreads();
#pragma unroll
        for (int j = 0; j < 8; ++j) {
            int f = j * 256 + tid;
            int r = f >> 6, kk = f & 63;
            xs[r][kk] = x[(size_t)(m0 + r) * D_ + k0 + kk];
            ws[r][kk] = (r < 16) ? WB[(size_t)r * D_ + k0 + kk]
                                 : WC[(size_t)(r - 16) * D_ + k0 + kk];
        }
        __syncthreads();
#pragma unroll 8
        for (int kk = 0; kk < 64; ++kk) {
            float wv = ws[o][kk];
#pragma unroll
            for (int r = 0; r < 4; ++r)
                acc[r] = fmaf(xs[mg * 4 + r][kk], wv, acc[r]);
        }
    }
#pragma unroll
    for (int r = 0; r < 4; ++r) {
        int m = m0 + mg * 4 + r;
        if (o < 16) Bm[(size_t)m * DS_ + o] = acc[r];
        else        Cm[(size_t)m * DS_ + (o - 16)] = acc[r];
    }
}

// ============ chunked scan, thread-owns-d layout ============
// pass 1 — per-chunk decay products P[s] and zero-input responses Z[s]
__global__ __launch_bounds__(256) void scan1_kernel(
    const u16* __restrict__ dt, const u16* __restrict__ xi,
    const float* __restrict__ Bm, const float* __restrict__ A_log,
    float* __restrict__ P, float* __restrict__ Z) {
    const int c = blockIdx.x, dblk = blockIdx.y, b = blockIdx.z;
    const int tid = threadIdx.x;
    const int d = dblk * 256 + tid;
    __shared__ u16 sdt[TT_ * 256];
    __shared__ u16 sxi[TT_ * 256];
    __shared__ float sB[TT_ * 16];
    float A2[16], st[16], Pp[16];
#pragma unroll
    for (int s = 0; s < 16; ++s) {
        A2[s] = -0.5f * __expf(A_log[(size_t)d * DS_ + s]);
        st[s] = 0.f; Pp[s] = 1.f;
    }
    const size_t tb = (size_t)b * T_;
    for (int t0 = c * CL_; t0 < (c + 1) * CL_; t0 += TT_) {
        __syncthreads();
#pragma unroll
        for (int r = 0; r < 4; ++r) {
            int flat = r * 2048 + tid * 8;
            int row = flat >> 8, col = flat & 255;
            const u16* s1 = dt + (tb + t0 + row) * DI_ + dblk * 256 + col;
            const u16* s2 = xi + (tb + t0 + row) * DI_ + dblk * 256 + col;
            __builtin_amdgcn_global_load_lds(
                (const __attribute__((address_space(1))) void*)s1,
                (__attribute__((address_space(3))) void*)(sdt + flat), 16, 0, 0);
            __builtin_amdgcn_global_load_lds(
                (const __attribute__((address_space(1))) void*)s2,
                (__attribute__((address_space(3))) void*)(sxi + flat), 16, 0, 0);
        }
        *(float2*)(sB + tid * 2) = *(const float2*)(Bm + (tb + t0) * DS_ + tid * 2);
        __syncthreads();
#pragma unroll 2
        for (int tt = 0; tt < TT_; ++tt) {
            float dtv = bf2f(sdt[tt * 256 + tid]);
            float xiv = bf2f(sxi[tt * 256 + tid]);
            float dxv = dtv * xiv;
            float bv[16];
            *(float4*)&bv[0]  = *(const float4*)(sB + tt * 16);
            *(float4*)&bv[4]  = *(const float4*)(sB + tt * 16 + 4);
            *(float4*)&bv[8]  = *(const float4*)(sB + tt * 16 + 8);
            *(float4*)&bv[12] = *(const float4*)(sB + tt * 16 + 12);
#pragma unroll
            for (int s = 0; s < 16; ++s) {
                float a2   = fmaf(dtv, -A2[s], 1.f);
                float inv  = __builtin_amdgcn_rcpf(a2);
                float abar = fmaf(2.f, inv, -1.f);
                st[s] = fmaf(abar, st[s], (inv * bv[s]) * dxv);
                Pp[s] *= abar;
            }
        }
    }
    size_t base = (((size_t)b * DI_ + d) * NC_ + c) * 16;
#pragma unroll
    for (int q = 0; q < 4; ++q) {
        *(float4*)(P + base + q * 4) = (float4){Pp[q*4], Pp[q*4+1], Pp[q*4+2], Pp[q*4+3]};
        *(float4*)(Z + base + q * 4) = (float4){st[q*4], st[q*4+1], st[q*4+2], st[q*4+3]};
    }
}

// pass 2 — serial combine over chunks; writes chunk-init states I in-place into P
__global__ __launch_bounds__(256) void scan2_kernel(
    float* __restrict__ P, const float* __restrict__ Z,
    float* __restrict__ st_out) {
    size_t idx = (size_t)blockIdx.x * 256 + threadIdx.x;   // (b*DI+d)*16+s
    size_t bd = idx >> 4;
    int s = (int)(idx & 15);
    float cur = 0.f;
    for (int c = 0; c < NC_; ++c) {
        size_t a = (bd * NC_ + c) * 16 + s;
        float p = P[a], zv = Z[a];
        P[a] = cur;                       // I: state at chunk start
        cur = fmaf(p, cur, zv);
    }
    st_out[idx] = cur;
}

// pass 3 — recompute with init states, emit dot-product outputs
__global__ __launch_bounds__(256) void scan3_kernel(
    const u16* __restrict__ dt, const u16* __restrict__ xi,
    const float* __restrict__ Bm, const float* __restrict__ Cm,
    const float* __restrict__ A_log, const float* __restrict__ I,
    u16* __restrict__ so) {
    const int c = blockIdx.x, dblk = blockIdx.y, b = blockIdx.z;
    const int tid = threadIdx.x;
    const int d = dblk * 256 + tid;
    __shared__ u16 sdt[TT_ * 256];
    __shared__ u16 sxi[TT_ * 256];
    __shared__ float sB[TT_ * 16];
    __shared__ float sC[TT_ * 16];
    float A2[16], st[16];
#pragma unroll
    for (int s = 0; s < 16; ++s)
        A2[s] = -0.5f * __expf(A_log[(size_t)d * DS_ + s]);
    size_t base = (((size_t)b * DI_ + d) * NC_ + c) * 16;
#pragma unroll
    for (int q = 0; q < 4; ++q) {
        float4 v = *(const float4*)(I + base + q * 4);
        st[q*4] = v.x; st[q*4+1] = v.y; st[q*4+2] = v.z; st[q*4+3] = v.w;
    }
    const size_t tb = (size_t)b * T_;
    for (int t0 = c * CL_; t0 < (c + 1) * CL_; t0 += TT_) {
        __syncthreads();
#pragma unroll
        for (int r = 0; r < 4; ++r) {
            int flat = r * 2048 + tid * 8;
            int row = flat >> 8, col = flat & 255;
            const u16* s1 = dt + (tb + t0 + row) * DI_ + dblk * 256 + col;
            const u16* s2 = xi + (tb + t0 + row) * DI_ + dblk * 256 + col;
            __builtin_amdgcn_global_load_lds(
                (const __attribute__((address_space(1))) void*)s1,
                (__attribute__((address_space(3))) void*)(sdt + flat), 16, 0, 0);
            __builtin_amdgcn_global_load_lds(
                (const __attribute__((address_space(1))) void*)s2,
                (__attribute__((address_space(3))) void*)(sxi + flat), 16, 0, 0);
        }
        *(float2*)(sB + tid * 2) = *(const float2*)(Bm + (tb + t0) * DS_ + tid * 2);
        *(float2*)(sC + tid * 2) = *(const float2*)(Cm + (tb + t0) * DS_ + tid * 2);
        __syncthreads();
#pragma unroll 2
        for (int tt = 0; tt < TT_; ++tt) {
            float dtv = bf2f(sdt[tt * 256 + tid]);
            float xiv = bf2f(sxi[tt * 256 + tid]);
            float dxv = dtv * xiv;
            float bv[16], cv[16];
            *(float4*)&bv[0]  = *(const float4*)(sB + tt * 16);
            *(float4*)&bv[4]  = *(const float4*)(sB + tt * 16 + 4);
            *(float4*)&bv[8]  = *(const float4*)(sB + tt * 16 + 8);
            *(float4*)&bv[12] = *(const float4*)(sB + tt * 16 + 12);
            *(float4*)&cv[0]  = *(const float4*)(sC + tt * 16);
            *(float4*)&cv[4]  = *(const float4*)(sC + tt * 16 + 4);
            *(float4*)&cv[8]  = *(const float4*)(sC + tt * 16 + 8);
            *(float4*)&cv[12] = *(const float4*)(sC + tt * 16 + 12);
            float acc = 0.f;
#pragma unroll
            for (int s = 0; s < 16; ++s) {
                float a2   = fmaf(dtv, -A2[s], 1.f);
                float inv  = __builtin_amdgcn_rcpf(a2);
                float abar = fmaf(2.f, inv, -1.f);
                st[s] = fmaf(abar, st[s], (inv * bv[s]) * dxv);
                acc = fmaf(st[s], cv[s], acc);
            }
            so[(tb + t0 + tt) * DI_ + d] = f2bf(acc);
        }
    }
}

// ---------------- gated LayerNorm -> bf16 normed ----------------
__global__ __launch_bounds__(256) void ln_kernel(
    const u16* __restrict__ so, const u16* __restrict__ z,
    const float* __restrict__ gamma, const float* __restrict__ beta,
    u16* __restrict__ normed) {
    int m = blockIdx.x;
    int tid = threadIdx.x;
    size_t base = (size_t)m * DI_;
    float v[8];
    float s = 0.f, s2 = 0.f;
#pragma unroll
    for (int j = 0; j < 8; ++j) {
        int i = tid + j * 256;
        float val = bf2f(so[base + i]) * bf2f(z[base + i]);
        v[j] = val; s += val; s2 += val * val;
    }
#pragma unroll
    for (int off = 32; off; off >>= 1) {
        s  += __shfl_xor(s,  off);
        s2 += __shfl_xor(s2, off);
    }
    __shared__ float rs[4], rq[4];
    int wave = tid >> 6;
    if ((tid & 63) == 0) { rs[wave] = s; rq[wave] = s2; }
    __syncthreads();
    s  = rs[0] + rs[1] + rs[2] + rs[3];
    s2 = rq[0] + rq[1] + rq[2] + rq[3];
    float mu  = s * (1.f / DI_);
    float var = s2 * (1.f / DI_) - mu * mu;
    float rstd = rsqrtf(var + 1e-5f);
#pragma unroll
    for (int j = 0; j < 8; ++j) {
        int i = tid + j * 256;
        float nv = (v[j] - mu) * rstd * gamma[i] + beta[i];
        normed[base + i] = f2bf(nv);
    }
}

extern "C" void kernel_launch(void* const* d_in, const int* in_sizes, int n_in,
                              void* d_out, int out_size, void* d_ws, size_t ws_size,
                              hipStream_t stream) {
    const float* x       = (const float*)d_in[0];
    const float* Win     = (const float*)d_in[1];
    const float* A_log   = (const float*)d_in[2];
    const float* WB      = (const float*)d_in[3];
    const float* WC      = (const float*)d_in[4];
    const float* Wdt     = (const float*)d_in[5];
    const float* bdt     = (const float*)d_in[6];
    const float* dt_bias = (const float*)d_in[7];
    const float* gamma   = (const float*)d_in[8];
    const float* beta    = (const float*)d_in[9];
    const float* Wout    = (const float*)d_in[10];

    float* y_out     = (float*)d_out;
    float* state_out = y_out + (size_t)B_ * T_ * D_;

    char* ws = (char*)d_ws;
    u16* xi_bf   = (u16*)(ws + 0);            // 16 MB
    u16* z_bf    = (u16*)(ws + 16777216);     // 16 MB
    u16* dt_bf   = (u16*)(ws + 33554432);     // 16 MB
    u16* so_bf   = (u16*)(ws + 50331648);     // 16 MB
    u16* nm_bf   = (u16*)(ws + 67108864);     // 16 MB
    u16* x_bf    = (u16*)(ws + 83886080);     // 8 MB  (dead after GEMMs -> P/I)
    u16* win_bf  = (u16*)(ws + 92274688);     // 8 MB  (dead after GEMMs -> Z)
    u16* wdt_bf  = (u16*)(ws + 100663296);    // 4 MB
    u16* wout_bf = (u16*)(ws + 104857600);    // 4 MB
    float* BmB   = (float*)(ws + 109051904);  // 256 KB
    float* CmB   = (float*)(ws + 109314048);  // 256 KB

    // P (8 MB, becomes I in-place) and Z (8 MB) alias dead x_bf / win_bf
    float* Pc = (float*)(ws + 83886080);
    float* Zc = (float*)(ws + 92274688);

    {
        int n4;
        n4 = (B_ * T_ * D_) / 4;
        cvt_kernel<<<(n4 + 255) / 256, 256, 0, stream>>>(x, x_bf, n4);
        n4 = (2 * DI_ * D_) / 4;
        cvt_kernel<<<(n4 + 255) / 256, 256, 0, stream>>>(Win, win_bf, n4);
        n4 = (DI_ * D_) / 4;
        cvt_kernel<<<(n4 + 255) / 256, 256, 0, stream>>>(Wdt, wdt_bf, n4);
        n4 = (D_ * DI_) / 4;
        cvt_kernel<<<(n4 + 255) / 256, 256, 0, stream>>>(Wout, wout_bf, n4);
    }

    // fused [xi | z | dt] : grid 48 x 16, 512 threads
    gemm_in<<<dim3(6144 / 128, MROWS / 256), dim3(512), 0, stream>>>(
        x_bf, win_bf, wdt_bf, xi_bf, z_bf, dt_bf, bdt, dt_bias);
    bc_kernel<<<MROWS / 32, 256, 0, stream>>>(x, WB, WC, BmB, CmB);

    // chunked scan (3 passes) — x_bf/win_bf dead from here
    scan1_kernel<<<dim3(NC_, DI_ / 256, B_), 256, 0, stream>>>(
        dt_bf, xi_bf, BmB, A_log, Pc, Zc);
    scan2_kernel<<<(B_ * DI_ * DS_) / 256, 256, 0, stream>>>(
        Pc, Zc, state_out);
    scan3_kernel<<<dim3(NC_, DI_ / 256, B_), 256, 0, stream>>>(
        dt_bf, xi_bf, BmB, CmB, A_log, Pc, so_bf);

    ln_kernel<<<MROWS, 256, 0, stream>>>(so_bf, z_bf, gamma, beta, nm_bf);
    gemm_out<<<dim3(D_ / 128, MROWS / 128), 256, 0, stream>>>(
        nm_bf, wout_bf, y_out, MROWS, D_, DI_);
}